// Round 14
// baseline (230.212 us; speedup 1.0000x reference)
//
#include <hip/hip_runtime.h>

typedef __attribute__((ext_vector_type(8))) short bf16x8;
typedef __attribute__((ext_vector_type(4))) float f32x4;

#define NB 196       // node buckets of 512
#define CAP 8192     // per-bucket edge capacity (avg 4096, sigma ~64)
#define SBLK 256     // bscatter blocks
#define ECH 3125     // edges per bscatter block
#define GEMM_BLOCKS 1563   // Npad/64

__device__ __forceinline__ unsigned short f2bf(float f) {
    unsigned int u = __float_as_uint(f);
    u = (u + 0x7FFFu + ((u >> 16) & 1u)) >> 16;   // RTNE
    return (unsigned short)u;
}
__device__ __forceinline__ float bf2f(unsigned short v) {
    return __uint_as_float(((unsigned int)v) << 16);
}

// ================= layer-1 GEMM body (BNW=128, fp32 A, NO dinv dependency) =================
__device__ __forceinline__ void gemm1_body(
    unsigned short* As, unsigned short* Bs, int bid,
    const float* __restrict__ Ag, const unsigned short* __restrict__ BTcat,
    const float* __restrict__ bias,
    unsigned short* __restrict__ Y0, unsigned short* __restrict__ Y1,
    unsigned short* __restrict__ Y2, int nrows)
{
    const int t  = threadIdx.x;
    const int w  = t >> 6, l = t & 63;
    const int g  = l >> 4, li = l & 15;
    const int wr = w >> 1, wc = w & 1;
    const int row0 = bid * 64;

    #pragma unroll
    for (int i = 0; i < 4; ++i) {
        const int q   = t + 256 * i;
        const int row = q >> 4;
        const int ck  = q & 15;
        unsigned short o[8];
        if (row0 + row < nrows) {
            const f32x4* src = (const f32x4*)(Ag + (size_t)(row0 + row) * 128 + ck * 8);
            const f32x4 a = __builtin_nontemporal_load(src);
            const f32x4 b = __builtin_nontemporal_load(src + 1);
            o[0]=f2bf(a.x); o[1]=f2bf(a.y); o[2]=f2bf(a.z); o[3]=f2bf(a.w);
            o[4]=f2bf(b.x); o[5]=f2bf(b.y); o[6]=f2bf(b.z); o[7]=f2bf(b.w);
        } else {
            #pragma unroll
            for (int u = 0; u < 8; ++u) o[u] = 0;
        }
        *(int4*)&As[row * 128 + ((ck ^ (row & 7)) << 3)] = *(int4*)o;
    }

    #pragma unroll 1
    for (int wgt = 0; wgt < 3; ++wgt) {
        __syncthreads();
        {
            const int4* Bg = (const int4*)(BTcat + (size_t)wgt * 128 * 128);
            #pragma unroll
            for (int i = 0; i < 8; ++i) {
                const int q   = t + 256 * i;
                const int row = q >> 4;
                const int ck  = q & 15;
                const int4 v  = Bg[q];
                *(int4*)&Bs[row * 128 + ((ck ^ (row & 7)) << 3)] = v;
            }
        }
        __syncthreads();

        f32x4 acc[2][4];
        #pragma unroll
        for (int rf = 0; rf < 2; ++rf)
            #pragma unroll
            for (int cf = 0; cf < 4; ++cf)
                acc[rf][cf] = (f32x4){0.f, 0.f, 0.f, 0.f};

        #pragma unroll
        for (int kk = 0; kk < 4; ++kk) {
            bf16x8 av[2], bv[4];
            #pragma unroll
            for (int rf = 0; rf < 2; ++rf) {
                const int ar = wr * 32 + rf * 16 + li;
                const int ck = (kk * 4 + g) ^ (ar & 7);
                av[rf] = *(const bf16x8*)&As[ar * 128 + (ck << 3)];
            }
            #pragma unroll
            for (int cf = 0; cf < 4; ++cf) {
                const int bc = wc * 64 + cf * 16 + li;
                const int ck = (kk * 4 + g) ^ (bc & 7);
                bv[cf] = *(const bf16x8*)&Bs[bc * 128 + (ck << 3)];
            }
            #pragma unroll
            for (int rf = 0; rf < 2; ++rf)
                #pragma unroll
                for (int cf = 0; cf < 4; ++cf)
                    acc[rf][cf] = __builtin_amdgcn_mfma_f32_16x16x32_bf16(
                        av[rf], bv[cf], acc[rf][cf], 0, 0, 0);
        }

        unsigned short* Y = (wgt == 0) ? Y0 : (wgt == 1) ? Y1 : Y2;
        #pragma unroll
        for (int rf = 0; rf < 2; ++rf) {
            #pragma unroll
            for (int i = 0; i < 4; ++i) {
                const int r = row0 + wr * 32 + rf * 16 + 4 * g + i;
                if (r < nrows) {
                    #pragma unroll
                    for (int cf = 0; cf < 4; ++cf) {
                        const int c = wc * 64 + cf * 16 + li;
                        float v = acc[rf][cf][i];
                        if (wgt == 0) v += bias[c];
                        Y[(size_t)r * 128 + c] = f2bf(v);
                    }
                }
            }
        }
    }
}

// ================= bscatter body (per-bucket edge streams) =================
__device__ __forceinline__ void bscatter_body(
    int* lds, int bid,
    const int* __restrict__ src, const int* __restrict__ dst,
    int* __restrict__ bcnt_in, int* __restrict__ bcnt_out,
    int* __restrict__ ebuf_in, int* __restrict__ ebuf_out, int E)
{
    int* lcnt_d  = lds;
    int* lcnt_s  = lds + NB;
    int* lbase_d = lds + 2 * NB;
    int* lbase_s = lds + 3 * NB;
    const int t = threadIdx.x;
    const int c0 = bid * ECH;
    const int c1 = min(E, c0 + ECH);
    for (int i = t; i < NB; i += 256) { lcnt_d[i] = 0; lcnt_s[i] = 0; }
    __syncthreads();
    for (int e = c0 + t; e < c1; e += 256) {
        atomicAdd(&lcnt_d[dst[e] >> 9], 1);
        atomicAdd(&lcnt_s[src[e] >> 9], 1);
    }
    __syncthreads();
    for (int b = t; b < NB; b += 256) {
        lbase_d[b] = atomicAdd(&bcnt_in[b],  lcnt_d[b]);
        lbase_s[b] = atomicAdd(&bcnt_out[b], lcnt_s[b]);
        lcnt_d[b] = 0; lcnt_s[b] = 0;
    }
    __syncthreads();
    for (int e = c0 + t; e < c1; e += 256) {
        const int s = src[e], d = dst[e];
        const int bd = d >> 9, bs = s >> 9;
        const int rd = atomicAdd(&lcnt_d[bd], 1);
        ebuf_in [bd * CAP + lbase_d[bd] + rd] = (s << 9) | (d & 511);
        const int rs = atomicAdd(&lcnt_s[bs], 1);
        ebuf_out[bs * CAP + lbase_s[bs] + rs] = (d << 9) | (s & 511);
    }
}

// ================= fused: bscatter (blocks 0..SBLK-1, start first) || layer-1 GEMM =================
__global__ __launch_bounds__(256)
void fused1_k(const float* __restrict__ x, const unsigned short* __restrict__ wt1,
              const float* __restrict__ b1,
              unsigned short* __restrict__ y1b, unsigned short* __restrict__ h_in,
              unsigned short* __restrict__ h_out,
              const int* __restrict__ src, const int* __restrict__ dst,
              int* __restrict__ bcnt_in, int* __restrict__ bcnt_out,
              int* __restrict__ ebuf_in, int* __restrict__ ebuf_out,
              int nrows, int E)
{
    __shared__ unsigned short lds[64 * 128 + 128 * 128];   // 48KB union
    if (blockIdx.x < SBLK) {
        bscatter_body((int*)lds, blockIdx.x,
                      src, dst, bcnt_in, bcnt_out, ebuf_in, ebuf_out, E);
    } else {
        gemm1_body(lds, lds + 64 * 128, blockIdx.x - SBLK,
                   x, wt1, b1, y1b, h_in, h_out, nrows);
    }
}

// ================= weight transpose + bcnt zero (fused, runs first) =================
__global__ __launch_bounds__(256)
void wtrans_all_k(const float* __restrict__ W1r, const float* __restrict__ W1i,
                  const float* __restrict__ W1o, const float* __restrict__ W2r,
                  const float* __restrict__ W2i, const float* __restrict__ W2o,
                  unsigned short* __restrict__ T1, unsigned short* __restrict__ T2,
                  int* __restrict__ bcnt)
{
    const int tid = blockIdx.x * 256 + threadIdx.x;   // 0..73727
    if (tid < 2 * NB) bcnt[tid] = 0;                  // fused zero of bucket counters
    if (tid >= 3 * 16384 + 3 * 8192) return;
    const float* W; unsigned short* T; int M, r, base;
    if (tid < 49152) {
        const int w = tid / 16384; r = tid % 16384; M = 128;
        W = (w == 0) ? W1r : (w == 1) ? W1i : W1o;
        T = T1; base = w * 128;
    } else {
        const int u = tid - 49152;
        const int w = u / 8192; r = u % 8192; M = 64;
        W = (w == 0) ? W2r : (w == 1) ? W2i : W2o;
        T = T2; base = w * 64;
    }
    const int m = r & (M - 1);
    const int k = r / M;
    T[(size_t)(base + m) * 128 + k] = f2bf(W[(size_t)k * M + m]);
}

// ================= per-bucket: inline bucket-scan + histogram -> dinv/rp + col fill =================
__global__ __launch_bounds__(512)
void bdegfill_k(const int* __restrict__ ebuf_in, const int* __restrict__ ebuf_out,
                const int* __restrict__ bcnt_in, const int* __restrict__ bcnt_out,
                float* __restrict__ dinv_in, float* __restrict__ dinv_out,
                int* __restrict__ rp_in, int* __restrict__ rp_out,
                int* __restrict__ col_in, int* __restrict__ col_out, int N, int E)
{
    __shared__ int cnt[512];
    __shared__ int cur[512];
    __shared__ int bsc[512];
    const int t = threadIdx.x;
    const int dir = (blockIdx.x >= NB) ? 1 : 0;
    const int b = blockIdx.x - dir * NB;
    const int* ebuf = dir ? ebuf_out : ebuf_in;
    const int* bcnt = dir ? bcnt_out : bcnt_in;

    bsc[t] = (t < NB) ? bcnt[t] : 0;
    __syncthreads();
    #pragma unroll
    for (int off = 1; off < 512; off <<= 1) {
        const int tv = (t >= off) ? bsc[t - off] : 0;
        __syncthreads();
        bsc[t] += tv;
        __syncthreads();
    }
    const int ne   = bcnt[b];
    const int base = bsc[b] - ne;
    const int e0 = b * CAP;

    cnt[t] = 0;
    __syncthreads();
    for (int j = t; j < ne; j += 512) atomicAdd(&cnt[ebuf[e0 + j] & 511], 1);
    __syncthreads();

    const int node = b * 512 + t;
    const int deg = cnt[t];
    float* dinv = dir ? dinv_out : dinv_in;
    if (node < N) dinv[node] = (deg > 0) ? rsqrtf((float)deg) : 0.f;

    #pragma unroll
    for (int off = 1; off < 512; off <<= 1) {
        const int tv = (t >= off) ? cnt[t - off] : 0;
        __syncthreads();
        cnt[t] += tv;
        __syncthreads();
    }
    int* rp = dir ? rp_out : rp_in;
    if (node < N) rp[node] = base + cnt[t] - deg;
    if (b == 0 && t == 0) rp[N] = E;
    cur[t] = cnt[t] - deg;
    __syncthreads();

    int* col = dir ? col_out : col_in;
    for (int j = t; j < ne; j += 512) {
        const int p = ebuf[e0 + j];
        const int slot = atomicAdd(&cur[p & 511], 1);
        col[base + slot] = p >> 9;
    }
}

// ================= helpers for gather =================
template<bool EDGE_W>
__device__ __forceinline__ void accum8w(float* acc, const int4 v, float w) {
    const unsigned short* pp = (const unsigned short*)&v;
    #pragma unroll
    for (int u = 0; u < 8; ++u) {
        if (EDGE_W) acc[u] = fmaf(w, bf2f(pp[u]), acc[u]);
        else        acc[u] += bf2f(pp[u]);
    }
}

// ================= FUSED layer-1 gather + ReLU + layer-2 GEMM (low-LDS) =================
// Each block owns 16 complete nodes (grid = N/16 = 6250 exact).
// Phase A: gather -> LDS xs[16][128] (4KB only). Phase B: MFMA with B-fragments
// loaded DIRECTLY from global wt2 (48KB, chip-wide L2-resident) — no Bs staging.
__global__ __launch_bounds__(256)
void gfused2_k(const unsigned short* __restrict__ h_in,
               const unsigned short* __restrict__ h_out,
               const int* __restrict__ rp_in,  const int* __restrict__ col_in,
               const int* __restrict__ rp_out, const int* __restrict__ col_out,
               const float* __restrict__ dinv_in, const float* __restrict__ dinv_out,
               const unsigned short* __restrict__ ybase,   // y1b [N][128]
               const unsigned short* __restrict__ wt2,     // [192][128] cat [root|in|out]
               const float* __restrict__ b2,
               unsigned short* __restrict__ y2b,
               unsigned short* __restrict__ h2_in,
               unsigned short* __restrict__ h2_out)
{
    __shared__ unsigned short xs[16 * 128];    // 4KB relu'd layer-1 output tile

    const int t  = threadIdx.x;
    const int ln = t >> 4;                 // local node 0..15
    const int n  = blockIdx.x * 16 + ln;   // always < N (grid exact)
    const int c8 = (t & 15) * 8;

    // ---- Phase A: gather ----
    const int bi = rp_in[n],  ei = rp_in[n + 1];
    const int bo = rp_out[n], eo = rp_out[n + 1];
    const float di = dinv_in[n], dq = dinv_out[n];
    const int4 yb4 = *(const int4*)(ybase + (size_t)n * 128 + c8);

    const unsigned short* hi = h_in + c8;
    const unsigned short* ho = h_out + c8;

    float acc_i[8] = {}, acc_o[8] = {};

    #pragma unroll 1
    for (int pass = 0; pass < 2; ++pass) {
        const int beg = pass ? bo : bi;
        const int end = pass ? eo : ei;
        const int* col = pass ? col_out : col_in;
        const float* dv = pass ? dinv_out : dinv_in;
        const unsigned short* h = pass ? ho : hi;
        float* acc = pass ? acc_o : acc_i;

        int j = beg;
        if (j + 4 <= end) {
            int c0 = col[j], c1 = col[j + 1], c2 = col[j + 2], c3 = col[j + 3];
            for (; j + 8 <= end; j += 4) {
                const float w0 = dv[c0], w1 = dv[c1], w2 = dv[c2], w3 = dv[c3];
                const int4 v0 = *(const int4*)(h + (size_t)c0 * 128);
                const int4 v1 = *(const int4*)(h + (size_t)c1 * 128);
                const int4 v2 = *(const int4*)(h + (size_t)c2 * 128);
                const int4 v3 = *(const int4*)(h + (size_t)c3 * 128);
                c0 = col[j + 4]; c1 = col[j + 5]; c2 = col[j + 6]; c3 = col[j + 7];
                accum8w<true>(acc, v0, w0); accum8w<true>(acc, v1, w1);
                accum8w<true>(acc, v2, w2); accum8w<true>(acc, v3, w3);
            }
            const float w0 = dv[c0], w1 = dv[c1], w2 = dv[c2], w3 = dv[c3];
            const int4 v0 = *(const int4*)(h + (size_t)c0 * 128);
            const int4 v1 = *(const int4*)(h + (size_t)c1 * 128);
            const int4 v2 = *(const int4*)(h + (size_t)c2 * 128);
            const int4 v3 = *(const int4*)(h + (size_t)c3 * 128);
            accum8w<true>(acc, v0, w0); accum8w<true>(acc, v1, w1);
            accum8w<true>(acc, v2, w2); accum8w<true>(acc, v3, w3);
            j += 4;
        }
        if (j < end) {
            const int rem = end - j;
            const int c0 = col[j];
            const int c1 = (rem > 1) ? col[j + 1] : c0;
            const int c2 = (rem > 2) ? col[j + 2] : c0;
            const float w0 = dv[c0], w1 = dv[c1], w2 = dv[c2];
            const int4 v0 = *(const int4*)(h + (size_t)c0 * 128);
            if (rem > 1) {
                const int4 v1 = *(const int4*)(h + (size_t)c1 * 128);
                accum8w<true>(acc, v1, w1);
            }
            if (rem > 2) {
                const int4 v2 = *(const int4*)(h + (size_t)c2 * 128);
                accum8w<true>(acc, v2, w2);
            }
            accum8w<true>(acc, v0, w0);
        }
    }

    {
        const unsigned short* yb = (const unsigned short*)&yb4;
        const float si = 0.5f * di, sq = 0.5f * dq;
        unsigned short o[8];
        #pragma unroll
        for (int u = 0; u < 8; ++u) {
            const float v = bf2f(yb[u]) + si * acc_i[u] + sq * acc_o[u];
            o[u] = f2bf(fmaxf(v, 0.f));
        }
        *(int4*)&xs[ln * 128 + (((t & 15) ^ (ln & 7)) << 3)] = *(int4*)o;
    }

    __syncthreads();

    // ---- Phase B: MFMA [16 rows][K=128] x [192 cols], B direct from global (L2-hit) ----
    const int w = t >> 6, l = t & 63;
    const int g = l >> 4, li = l & 15;

    f32x4 acc2[3];
    #pragma unroll
    for (int cf = 0; cf < 3; ++cf) acc2[cf] = (f32x4){0.f, 0.f, 0.f, 0.f};

    #pragma unroll
    for (int kk = 0; kk < 4; ++kk) {
        const int cka = (kk * 4 + g) ^ (li & 7);
        const bf16x8 av = *(const bf16x8*)&xs[li * 128 + (cka << 3)];
        bf16x8 bv[3];
        #pragma unroll
        for (int cf = 0; cf < 3; ++cf) {
            const int bc = w * 48 + cf * 16 + li;
            bv[cf] = *(const bf16x8*)&wt2[(size_t)bc * 128 + (kk * 4 + g) * 8];
        }
        #pragma unroll
        for (int cf = 0; cf < 3; ++cf)
            acc2[cf] = __builtin_amdgcn_mfma_f32_16x16x32_bf16(av, bv[cf], acc2[cf], 0, 0, 0);
    }

    // ---- epilogue: c = w*48 + cf*16 + li; sel uniform per (w,cf) ----
    #pragma unroll
    for (int cf = 0; cf < 3; ++cf) {
        const int c   = w * 48 + cf * 16 + li;
        const int sel = c >> 6;
        const int cc  = c & 63;
        #pragma unroll
        for (int i = 0; i < 4; ++i) {
            const int node = blockIdx.x * 16 + 4 * g + i;
            const float vv = acc2[cf][i];
            if (sel == 0)
                y2b[(size_t)node * 64 + cc] = f2bf(vv + b2[cc]);
            else if (sel == 1)
                h2_in[(size_t)node * 64 + cc] = f2bf(vv * 0.5f * dinv_in[node]);
            else
                h2_out[(size_t)node * 64 + cc] = f2bf(vv * 0.5f * dinv_out[node]);
        }
    }
}

// ================= final gather (layer 2, F=64, prescaled h, fp32 out) =================
__global__ __launch_bounds__(256)
void gatherf_k(const unsigned short* __restrict__ h2_in,
               const unsigned short* __restrict__ h2_out,
               const int* __restrict__ rp_in,  const int* __restrict__ col_in,
               const int* __restrict__ rp_out, const int* __restrict__ col_out,
               const float* __restrict__ dinv_in, const float* __restrict__ dinv_out,
               const unsigned short* __restrict__ ybase, float* __restrict__ yout, int N)
{
    constexpr int F = 64, TPN = 8;
    const int tid = blockIdx.x * 256 + threadIdx.x;
    const int n = tid / TPN;
    if (n >= N) return;
    const int c8 = (tid % TPN) * 8;

    const int bi = rp_in[n],  ei = rp_in[n + 1];
    const int bo = rp_out[n], eo = rp_out[n + 1];
    const float di = dinv_in[n], dq = dinv_out[n];
    const int4 yb4 = *(const int4*)(ybase + (size_t)n * F + c8);

    const unsigned short* hi = h2_in + c8;
    const unsigned short* ho = h2_out + c8;

    float acc_i[8] = {}, acc_o[8] = {};

    #pragma unroll 1
    for (int pass = 0; pass < 2; ++pass) {
        const int beg = pass ? bo : bi;
        const int end = pass ? eo : ei;
        const int* col = pass ? col_out : col_in;
        const unsigned short* h = pass ? ho : hi;
        float* acc = pass ? acc_o : acc_i;

        int j = beg;
        if (j + 4 <= end) {
            int c0 = col[j], c1 = col[j + 1], c2 = col[j + 2], c3 = col[j + 3];
            for (; j + 8 <= end; j += 4) {
                const int4 v0 = *(const int4*)(h + (size_t)c0 * F);
                const int4 v1 = *(const int4*)(h + (size_t)c1 * F);
                const int4 v2 = *(const int4*)(h + (size_t)c2 * F);
                const int4 v3 = *(const int4*)(h + (size_t)c3 * F);
                c0 = col[j + 4]; c1 = col[j + 5]; c2 = col[j + 6]; c3 = col[j + 7];
                accum8w<false>(acc, v0, 0.f); accum8w<false>(acc, v1, 0.f);
                accum8w<false>(acc, v2, 0.f); accum8w<false>(acc, v3, 0.f);
            }
            const int4 v0 = *(const int4*)(h + (size_t)c0 * F);
            const int4 v1 = *(const int4*)(h + (size_t)c1 * F);
            const int4 v2 = *(const int4*)(h + (size_t)c2 * F);
            const int4 v3 = *(const int4*)(h + (size_t)c3 * F);
            accum8w<false>(acc, v0, 0.f); accum8w<false>(acc, v1, 0.f);
            accum8w<false>(acc, v2, 0.f); accum8w<false>(acc, v3, 0.f);
            j += 4;
        }
        if (j < end) {
            const int rem = end - j;
            const int c0 = col[j];
            const int c1 = (rem > 1) ? col[j + 1] : c0;
            const int c2 = (rem > 2) ? col[j + 2] : c0;
            const int4 v0 = *(const int4*)(h + (size_t)c0 * F);
            if (rem > 1) {
                const int4 v1 = *(const int4*)(h + (size_t)c1 * F);
                accum8w<false>(acc, v1, 0.f);
            }
            if (rem > 2) {
                const int4 v2 = *(const int4*)(h + (size_t)c2 * F);
                accum8w<false>(acc, v2, 0.f);
            }
            accum8w<false>(acc, v0, 0.f);
        }
    }

    const unsigned short* yb = (const unsigned short*)&yb4;
    float v[8];
    #pragma unroll
    for (int u = 0; u < 8; ++u)
        v[u] = bf2f(yb[u]) + di * acc_i[u] + dq * acc_o[u];

    f32x4* yp = (f32x4*)(yout + (size_t)n * F + c8);
    __builtin_nontemporal_store((f32x4){v[0], v[1], v[2], v[3]}, yp);
    __builtin_nontemporal_store((f32x4){v[4], v[5], v[6], v[7]}, yp + 1);
}

// ================= launch =================
extern "C" void kernel_launch(void* const* d_in, const int* in_sizes, int n_in,
                              void* d_out, int out_size, void* d_ws, size_t ws_size,
                              hipStream_t stream)
{
    const int N = 100000, E = 800000, C = 64, H = 128;
    const int Npad = ((N + 63) / 64) * 64;          // 100032

    const float* x       = (const float*)d_in[0];
    const int*   ei      = (const int*)d_in[1];
    const int*   src     = ei;
    const int*   dst     = ei + E;
    const float* W1_in   = (const float*)d_in[2];
    const float* W1_out  = (const float*)d_in[3];
    const float* W1_root = (const float*)d_in[4];
    const float* b1      = (const float*)d_in[5];
    const float* W2_in   = (const float*)d_in[6];
    const float* W2_out  = (const float*)d_in[7];
    const float* W2_root = (const float*)d_in[8];
    const float* b2      = (const float*)d_in[9];
    float* out = (float*)d_out;

    // ---- workspace layout ----
    char* p = (char*)d_ws;
    int*   bcnt_in  = (int*)p;            p += (size_t)(2 * NB + 8) * 4;
    int*   bcnt_out = bcnt_in + NB;
    float* dinv_in  = (float*)p;          p += (size_t)N * 4;
    float* dinv_out = (float*)p;          p += (size_t)N * 4;
    int*   rp_in    = (int*)p;            p += (size_t)(N + 8) * 4;
    int*   rp_out   = (int*)p;            p += (size_t)(N + 8) * 4;
    int*   col_in   = (int*)p;            p += (size_t)E * 4;
    int*   col_out  = (int*)p;            p += (size_t)E * 4;
    int*   ebuf_in  = (int*)p;            p += (size_t)NB * CAP * 4;   // dead after bdegfill
    int*   ebuf_out = (int*)p;            p += (size_t)NB * CAP * 4;   //  -> y2b aliases here
    unsigned short* wt1 = (unsigned short*)p;       p += (size_t)384 * 128 * 2;
    unsigned short* wt2 = (unsigned short*)p;       p += (size_t)192 * 128 * 2;
    unsigned short* h2buf = (unsigned short*)p;     p += (size_t)Npad * 128 * 2;  // h2_in|h2_out
    unsigned short* y1b = (unsigned short*)p;       p += (size_t)Npad * 128 * 2;  // root outputs L1
    unsigned short* h_in = (unsigned short*)p;      p += (size_t)Npad * 128 * 2;
    unsigned short* h_out= (unsigned short*)p;      p += (size_t)Npad * 128 * 2;

    unsigned short* y2b    = (unsigned short*)ebuf_in;     // 12.80MB <= 12.84MB ebuf
    unsigned short* h2_in  = h2buf;                        // Npad*64 each
    unsigned short* h2_out = h2buf + (size_t)Npad * 64;

    const dim3 blk(256);

    // ---- weights + bcnt zero (independent, first) ----
    wtrans_all_k<<<288, blk, 0, stream>>>(W1_root, W1_in, W1_out, W2_root, W2_in, W2_out,
                                          wt1, wt2, bcnt_in);

    // ---- fused: bscatter (blocks 0..255) || layer-1 GEMM (no dinv dependency) ----
    fused1_k<<<SBLK + GEMM_BLOCKS, blk, 0, stream>>>(
        x, wt1, b1, y1b, h_in, h_out,
        src, dst, bcnt_in, bcnt_out, ebuf_in, ebuf_out, N, E);

    // ---- per-bucket build (inline bucket scan): dinv, rp, col ----
    bdegfill_k<<<2 * NB, 512, 0, stream>>>(ebuf_in, ebuf_out, bcnt_in, bcnt_out,
                                           dinv_in, dinv_out,
                                           rp_in, rp_out, col_in, col_out, N, E);

    // ---- fused layer-1 gather + ReLU + layer-2 GEMM (16 nodes/block, exact) ----
    gfused2_k<<<N / 16, blk, 0, stream>>>(
        h_in, h_out, rp_in, col_in, rp_out, col_out,
        dinv_in, dinv_out, y1b, wt2, b2, y2b, h2_in, h2_out);

    // ---- final gather (layer 2) ----
    const int ga2 = (N * (C / 8) + 255) / 256;
    gatherf_k<<<ga2, blk, 0, stream>>>(
        h2_in, h2_out, rp_in, col_in, rp_out, col_out,
        dinv_in, dinv_out, y2b, out, N);
}

// Round 15
// 215.721 us; speedup vs baseline: 1.0672x; 1.0672x over previous
//
#include <hip/hip_runtime.h>

typedef __attribute__((ext_vector_type(8))) short bf16x8;
typedef __attribute__((ext_vector_type(4))) float f32x4;

#define NB 196       // node buckets of 512
#define CAP 8192     // per-bucket edge capacity (avg 4096, sigma ~64)
#define SBLK 256     // bscatter blocks
#define ECH 3125     // edges per bscatter block
#define GEMM_BLOCKS 1563   // Npad/64

__device__ __forceinline__ unsigned short f2bf(float f) {
    unsigned int u = __float_as_uint(f);
    u = (u + 0x7FFFu + ((u >> 16) & 1u)) >> 16;   // RTNE
    return (unsigned short)u;
}
__device__ __forceinline__ float bf2f(unsigned short v) {
    return __uint_as_float(((unsigned int)v) << 16);
}

// ================= layer-1 GEMM body (BNW=128, fp32 A, NO dinv dependency) =================
// wgt=0: +bias -> y1b;  wgt=1 -> h_in (unscaled);  wgt=2 -> h_out (unscaled)
__device__ __forceinline__ void gemm1_body(
    unsigned short* As, unsigned short* Bs, int bid,
    const float* __restrict__ Ag, const unsigned short* __restrict__ BTcat,
    const float* __restrict__ bias,
    unsigned short* __restrict__ Y0, unsigned short* __restrict__ Y1,
    unsigned short* __restrict__ Y2, int nrows)
{
    const int t  = threadIdx.x;
    const int w  = t >> 6, l = t & 63;
    const int g  = l >> 4, li = l & 15;
    const int wr = w >> 1, wc = w & 1;
    const int row0 = bid * 64;

    #pragma unroll
    for (int i = 0; i < 4; ++i) {
        const int q   = t + 256 * i;
        const int row = q >> 4;
        const int ck  = q & 15;
        unsigned short o[8];
        if (row0 + row < nrows) {
            const f32x4* src = (const f32x4*)(Ag + (size_t)(row0 + row) * 128 + ck * 8);
            const f32x4 a = __builtin_nontemporal_load(src);
            const f32x4 b = __builtin_nontemporal_load(src + 1);
            o[0]=f2bf(a.x); o[1]=f2bf(a.y); o[2]=f2bf(a.z); o[3]=f2bf(a.w);
            o[4]=f2bf(b.x); o[5]=f2bf(b.y); o[6]=f2bf(b.z); o[7]=f2bf(b.w);
        } else {
            #pragma unroll
            for (int u = 0; u < 8; ++u) o[u] = 0;
        }
        *(int4*)&As[row * 128 + ((ck ^ (row & 7)) << 3)] = *(int4*)o;
    }

    #pragma unroll 1
    for (int wgt = 0; wgt < 3; ++wgt) {
        __syncthreads();
        {
            const int4* Bg = (const int4*)(BTcat + (size_t)wgt * 128 * 128);
            #pragma unroll
            for (int i = 0; i < 8; ++i) {
                const int q   = t + 256 * i;
                const int row = q >> 4;
                const int ck  = q & 15;
                const int4 v  = Bg[q];
                *(int4*)&Bs[row * 128 + ((ck ^ (row & 7)) << 3)] = v;
            }
        }
        __syncthreads();

        f32x4 acc[2][4];
        #pragma unroll
        for (int rf = 0; rf < 2; ++rf)
            #pragma unroll
            for (int cf = 0; cf < 4; ++cf)
                acc[rf][cf] = (f32x4){0.f, 0.f, 0.f, 0.f};

        #pragma unroll
        for (int kk = 0; kk < 4; ++kk) {
            bf16x8 av[2], bv[4];
            #pragma unroll
            for (int rf = 0; rf < 2; ++rf) {
                const int ar = wr * 32 + rf * 16 + li;
                const int ck = (kk * 4 + g) ^ (ar & 7);
                av[rf] = *(const bf16x8*)&As[ar * 128 + (ck << 3)];
            }
            #pragma unroll
            for (int cf = 0; cf < 4; ++cf) {
                const int bc = wc * 64 + cf * 16 + li;
                const int ck = (kk * 4 + g) ^ (bc & 7);
                bv[cf] = *(const bf16x8*)&Bs[bc * 128 + (ck << 3)];
            }
            #pragma unroll
            for (int rf = 0; rf < 2; ++rf)
                #pragma unroll
                for (int cf = 0; cf < 4; ++cf)
                    acc[rf][cf] = __builtin_amdgcn_mfma_f32_16x16x32_bf16(
                        av[rf], bv[cf], acc[rf][cf], 0, 0, 0);
        }

        unsigned short* Y = (wgt == 0) ? Y0 : (wgt == 1) ? Y1 : Y2;
        #pragma unroll
        for (int rf = 0; rf < 2; ++rf) {
            #pragma unroll
            for (int i = 0; i < 4; ++i) {
                const int r = row0 + wr * 32 + rf * 16 + 4 * g + i;
                if (r < nrows) {
                    #pragma unroll
                    for (int cf = 0; cf < 4; ++cf) {
                        const int c = wc * 64 + cf * 16 + li;
                        float v = acc[rf][cf][i];
                        if (wgt == 0) v += bias[c];
                        Y[(size_t)r * 128 + c] = f2bf(v);
                    }
                }
            }
        }
    }
}

// ================= bscatter body (per-bucket edge streams) =================
__device__ __forceinline__ void bscatter_body(
    int* lds, int bid,
    const int* __restrict__ src, const int* __restrict__ dst,
    int* __restrict__ bcnt_in, int* __restrict__ bcnt_out,
    int* __restrict__ ebuf_in, int* __restrict__ ebuf_out, int E)
{
    int* lcnt_d  = lds;
    int* lcnt_s  = lds + NB;
    int* lbase_d = lds + 2 * NB;
    int* lbase_s = lds + 3 * NB;
    const int t = threadIdx.x;
    const int c0 = bid * ECH;
    const int c1 = min(E, c0 + ECH);
    for (int i = t; i < NB; i += 256) { lcnt_d[i] = 0; lcnt_s[i] = 0; }
    __syncthreads();
    for (int e = c0 + t; e < c1; e += 256) {
        atomicAdd(&lcnt_d[dst[e] >> 9], 1);
        atomicAdd(&lcnt_s[src[e] >> 9], 1);
    }
    __syncthreads();
    for (int b = t; b < NB; b += 256) {
        lbase_d[b] = atomicAdd(&bcnt_in[b],  lcnt_d[b]);
        lbase_s[b] = atomicAdd(&bcnt_out[b], lcnt_s[b]);
        lcnt_d[b] = 0; lcnt_s[b] = 0;
    }
    __syncthreads();
    for (int e = c0 + t; e < c1; e += 256) {
        const int s = src[e], d = dst[e];
        const int bd = d >> 9, bs = s >> 9;
        const int rd = atomicAdd(&lcnt_d[bd], 1);
        ebuf_in [bd * CAP + lbase_d[bd] + rd] = (s << 9) | (d & 511);
        const int rs = atomicAdd(&lcnt_s[bs], 1);
        ebuf_out[bs * CAP + lbase_s[bs] + rs] = (d << 9) | (s & 511);
    }
}

// ================= fused: bscatter (blocks 0..SBLK-1, start first) || layer-1 GEMM =================
__global__ __launch_bounds__(256)
void fused1_k(const float* __restrict__ x, const unsigned short* __restrict__ wt1,
              const float* __restrict__ b1,
              unsigned short* __restrict__ y1b, unsigned short* __restrict__ h_in,
              unsigned short* __restrict__ h_out,
              const int* __restrict__ src, const int* __restrict__ dst,
              int* __restrict__ bcnt_in, int* __restrict__ bcnt_out,
              int* __restrict__ ebuf_in, int* __restrict__ ebuf_out,
              int nrows, int E)
{
    __shared__ unsigned short lds[64 * 128 + 128 * 128];   // 48KB union
    if (blockIdx.x < SBLK) {
        bscatter_body((int*)lds, blockIdx.x,
                      src, dst, bcnt_in, bcnt_out, ebuf_in, ebuf_out, E);
    } else {
        gemm1_body(lds, lds + 64 * 128, blockIdx.x - SBLK,
                   x, wt1, b1, y1b, h_in, h_out, nrows);
    }
}

// ================= layer-2 GEMM (bf16 A, BNW=64; dinv prescale — dinv ready) =================
__global__ __launch_bounds__(256)
void gemm2_k(const unsigned short* __restrict__ Axb,
             const unsigned short* __restrict__ BTcat,
             const float* __restrict__ bias,
             const float* __restrict__ dinv_in, const float* __restrict__ dinv_out,
             unsigned short* __restrict__ Y0, unsigned short* __restrict__ Y1,
             unsigned short* __restrict__ Y2, int nrows)
{
    __shared__ unsigned short As[64 * 128];
    __shared__ unsigned short Bs[64 * 128];

    const int t  = threadIdx.x;
    const int w  = t >> 6, l = t & 63;
    const int g  = l >> 4, li = l & 15;
    const int wr = w >> 1, wc = w & 1;
    const int row0 = blockIdx.x * 64;

    {
        const int4* Ag = (const int4*)(Axb + (size_t)row0 * 128);
        #pragma unroll
        for (int i = 0; i < 4; ++i) {
            const int q   = t + 256 * i;
            const int row = q >> 4;
            const int ck  = q & 15;
            const int4 v  = Ag[q];
            *(int4*)&As[row * 128 + ((ck ^ (row & 7)) << 3)] = v;
        }
    }

    #pragma unroll 1
    for (int wgt = 0; wgt < 3; ++wgt) {
        __syncthreads();
        {
            const int4* Bg = (const int4*)(BTcat + (size_t)wgt * 64 * 128);
            #pragma unroll
            for (int i = 0; i < 4; ++i) {
                const int q   = t + 256 * i;
                const int row = q >> 4;
                const int ck  = q & 15;
                const int4 v  = Bg[q];
                *(int4*)&Bs[row * 128 + ((ck ^ (row & 7)) << 3)] = v;
            }
        }
        __syncthreads();

        f32x4 acc[2][2];
        #pragma unroll
        for (int rf = 0; rf < 2; ++rf)
            #pragma unroll
            for (int cf = 0; cf < 2; ++cf)
                acc[rf][cf] = (f32x4){0.f, 0.f, 0.f, 0.f};

        #pragma unroll
        for (int kk = 0; kk < 4; ++kk) {
            bf16x8 av[2], bv[2];
            #pragma unroll
            for (int rf = 0; rf < 2; ++rf) {
                const int ar = wr * 32 + rf * 16 + li;
                const int ck = (kk * 4 + g) ^ (ar & 7);
                av[rf] = *(const bf16x8*)&As[ar * 128 + (ck << 3)];
            }
            #pragma unroll
            for (int cf = 0; cf < 2; ++cf) {
                const int bc = wc * 32 + cf * 16 + li;
                const int ck = (kk * 4 + g) ^ (bc & 7);
                bv[cf] = *(const bf16x8*)&Bs[bc * 128 + (ck << 3)];
            }
            #pragma unroll
            for (int rf = 0; rf < 2; ++rf)
                #pragma unroll
                for (int cf = 0; cf < 2; ++cf)
                    acc[rf][cf] = __builtin_amdgcn_mfma_f32_16x16x32_bf16(
                        av[rf], bv[cf], acc[rf][cf], 0, 0, 0);
        }

        unsigned short* Y = (wgt == 0) ? Y0 : (wgt == 1) ? Y1 : Y2;
        const float* dv = (wgt == 1) ? dinv_in : dinv_out;
        #pragma unroll
        for (int rf = 0; rf < 2; ++rf) {
            #pragma unroll
            for (int i = 0; i < 4; ++i) {
                const int r = row0 + wr * 32 + rf * 16 + 4 * g + i;
                if (r < nrows) {
                    const float s = (wgt == 0) ? 1.f : 0.5f * dv[r];
                    #pragma unroll
                    for (int cf = 0; cf < 2; ++cf) {
                        const int c = wc * 32 + cf * 16 + li;
                        float v = acc[rf][cf][i];
                        v = (wgt == 0) ? (v + bias[c]) : (v * s);
                        Y[(size_t)r * 64 + c] = f2bf(v);
                    }
                }
            }
        }
    }
}

// ================= weight transpose + bcnt zero (fused, runs first) =================
__global__ __launch_bounds__(256)
void wtrans_all_k(const float* __restrict__ W1r, const float* __restrict__ W1i,
                  const float* __restrict__ W1o, const float* __restrict__ W2r,
                  const float* __restrict__ W2i, const float* __restrict__ W2o,
                  unsigned short* __restrict__ T1, unsigned short* __restrict__ T2,
                  int* __restrict__ bcnt)
{
    const int tid = blockIdx.x * 256 + threadIdx.x;   // 0..73727
    if (tid < 2 * NB) bcnt[tid] = 0;                  // fused zero of bucket counters
    if (tid >= 3 * 16384 + 3 * 8192) return;
    const float* W; unsigned short* T; int M, r, base;
    if (tid < 49152) {
        const int w = tid / 16384; r = tid % 16384; M = 128;
        W = (w == 0) ? W1r : (w == 1) ? W1i : W1o;
        T = T1; base = w * 128;
    } else {
        const int u = tid - 49152;
        const int w = u / 8192; r = u % 8192; M = 64;
        W = (w == 0) ? W2r : (w == 1) ? W2i : W2o;
        T = T2; base = w * 64;
    }
    const int m = r & (M - 1);
    const int k = r / M;
    T[(size_t)(base + m) * 128 + k] = f2bf(W[(size_t)k * M + m]);
}

// ================= per-bucket: inline bucket-scan + histogram -> dinv/rp + col fill =================
__global__ __launch_bounds__(512)
void bdegfill_k(const int* __restrict__ ebuf_in, const int* __restrict__ ebuf_out,
                const int* __restrict__ bcnt_in, const int* __restrict__ bcnt_out,
                float* __restrict__ dinv_in, float* __restrict__ dinv_out,
                int* __restrict__ rp_in, int* __restrict__ rp_out,
                int* __restrict__ col_in, int* __restrict__ col_out, int N, int E)
{
    __shared__ int cnt[512];
    __shared__ int cur[512];
    __shared__ int bsc[512];
    const int t = threadIdx.x;
    const int dir = (blockIdx.x >= NB) ? 1 : 0;
    const int b = blockIdx.x - dir * NB;
    const int* ebuf = dir ? ebuf_out : ebuf_in;
    const int* bcnt = dir ? bcnt_out : bcnt_in;

    bsc[t] = (t < NB) ? bcnt[t] : 0;
    __syncthreads();
    #pragma unroll
    for (int off = 1; off < 512; off <<= 1) {
        const int tv = (t >= off) ? bsc[t - off] : 0;
        __syncthreads();
        bsc[t] += tv;
        __syncthreads();
    }
    const int ne   = bcnt[b];
    const int base = bsc[b] - ne;
    const int e0 = b * CAP;

    cnt[t] = 0;
    __syncthreads();
    for (int j = t; j < ne; j += 512) atomicAdd(&cnt[ebuf[e0 + j] & 511], 1);
    __syncthreads();

    const int node = b * 512 + t;
    const int deg = cnt[t];
    float* dinv = dir ? dinv_out : dinv_in;
    if (node < N) dinv[node] = (deg > 0) ? rsqrtf((float)deg) : 0.f;

    #pragma unroll
    for (int off = 1; off < 512; off <<= 1) {
        const int tv = (t >= off) ? cnt[t - off] : 0;
        __syncthreads();
        cnt[t] += tv;
        __syncthreads();
    }
    int* rp = dir ? rp_out : rp_in;
    if (node < N) rp[node] = base + cnt[t] - deg;
    if (b == 0 && t == 0) rp[N] = E;
    cur[t] = cnt[t] - deg;
    __syncthreads();

    int* col = dir ? col_out : col_in;
    for (int j = t; j < ne; j += 512) {
        const int p = ebuf[e0 + j];
        const int slot = atomicAdd(&cur[p & 511], 1);
        col[base + slot] = p >> 9;
    }
}

// ================= fused 2-direction gather =================
// EDGE_W=true  (layer 1): h unscaled; acc += dinv[col]*h[col]; v = yb + 0.5*dinv[n]*acc
// EDGE_W=false (layer 2): h prescaled by 0.5*dinv;  acc += h[col]; v = yb + dinv[n]*acc
template<bool EDGE_W>
__device__ __forceinline__ void accum8w(float* acc, const int4 v, float w) {
    const unsigned short* pp = (const unsigned short*)&v;
    #pragma unroll
    for (int u = 0; u < 8; ++u) {
        if (EDGE_W) acc[u] = fmaf(w, bf2f(pp[u]), acc[u]);
        else        acc[u] += bf2f(pp[u]);
    }
}

template<int F, bool RELU_BF16, bool EDGE_W>
__global__ __launch_bounds__(256)
void gather2_k(const unsigned short* __restrict__ h_in,
               const unsigned short* __restrict__ h_out,
               const int* __restrict__ rp_in,  const int* __restrict__ col_in,
               const int* __restrict__ rp_out, const int* __restrict__ col_out,
               const float* __restrict__ dinv_in, const float* __restrict__ dinv_out,
               const unsigned short* __restrict__ ybase, void* __restrict__ yout, int N)
{
    constexpr int TPN = F / 8;
    const int tid = blockIdx.x * 256 + threadIdx.x;
    const int n = tid / TPN;
    if (n >= N) return;
    const int c8 = (tid % TPN) * 8;

    const int bi = rp_in[n],  ei = rp_in[n + 1];
    const int bo = rp_out[n], eo = rp_out[n + 1];
    const float di = dinv_in[n], dq = dinv_out[n];
    const int4 yb4 = *(const int4*)(ybase + (size_t)n * F + c8);

    const unsigned short* hi = h_in + c8;
    const unsigned short* ho = h_out + c8;

    float acc_i[8] = {}, acc_o[8] = {};

    #pragma unroll 1
    for (int pass = 0; pass < 2; ++pass) {
        const int beg = pass ? bo : bi;
        const int end = pass ? eo : ei;
        const int* col = pass ? col_out : col_in;
        const float* dv = pass ? dinv_out : dinv_in;   // source-side dinv (same-direction array)
        const unsigned short* h = pass ? ho : hi;
        float* acc = pass ? acc_o : acc_i;

        int j = beg;
        if (j + 4 <= end) {
            int c0 = col[j], c1 = col[j + 1], c2 = col[j + 2], c3 = col[j + 3];
            for (; j + 8 <= end; j += 4) {
                float w0 = 0.f, w1 = 0.f, w2 = 0.f, w3 = 0.f;
                if (EDGE_W) { w0 = dv[c0]; w1 = dv[c1]; w2 = dv[c2]; w3 = dv[c3]; }
                const int4 v0 = *(const int4*)(h + (size_t)c0 * F);
                const int4 v1 = *(const int4*)(h + (size_t)c1 * F);
                const int4 v2 = *(const int4*)(h + (size_t)c2 * F);
                const int4 v3 = *(const int4*)(h + (size_t)c3 * F);
                c0 = col[j + 4]; c1 = col[j + 5]; c2 = col[j + 6]; c3 = col[j + 7];
                accum8w<EDGE_W>(acc, v0, w0); accum8w<EDGE_W>(acc, v1, w1);
                accum8w<EDGE_W>(acc, v2, w2); accum8w<EDGE_W>(acc, v3, w3);
            }
            float w0 = 0.f, w1 = 0.f, w2 = 0.f, w3 = 0.f;
            if (EDGE_W) { w0 = dv[c0]; w1 = dv[c1]; w2 = dv[c2]; w3 = dv[c3]; }
            const int4 v0 = *(const int4*)(h + (size_t)c0 * F);
            const int4 v1 = *(const int4*)(h + (size_t)c1 * F);
            const int4 v2 = *(const int4*)(h + (size_t)c2 * F);
            const int4 v3 = *(const int4*)(h + (size_t)c3 * F);
            accum8w<EDGE_W>(acc, v0, w0); accum8w<EDGE_W>(acc, v1, w1);
            accum8w<EDGE_W>(acc, v2, w2); accum8w<EDGE_W>(acc, v3, w3);
            j += 4;
        }
        if (j < end) {
            const int rem = end - j;
            const int c0 = col[j];
            const int c1 = (rem > 1) ? col[j + 1] : c0;
            const int c2 = (rem > 2) ? col[j + 2] : c0;
            float w0 = 0.f, w1 = 0.f, w2 = 0.f;
            if (EDGE_W) { w0 = dv[c0]; w1 = dv[c1]; w2 = dv[c2]; }
            const int4 v0 = *(const int4*)(h + (size_t)c0 * F);
            if (rem > 1) {
                const int4 v1 = *(const int4*)(h + (size_t)c1 * F);
                accum8w<EDGE_W>(acc, v1, w1);
            }
            if (rem > 2) {
                const int4 v2 = *(const int4*)(h + (size_t)c2 * F);
                accum8w<EDGE_W>(acc, v2, w2);
            }
            accum8w<EDGE_W>(acc, v0, w0);
        }
    }

    const unsigned short* yb = (const unsigned short*)&yb4;
    const float si = EDGE_W ? 0.5f * di : di;
    const float sq = EDGE_W ? 0.5f * dq : dq;
    float v[8];
    #pragma unroll
    for (int u = 0; u < 8; ++u)
        v[u] = bf2f(yb[u]) + si * acc_i[u] + sq * acc_o[u];

    if (RELU_BF16) {
        unsigned short o[8];
        #pragma unroll
        for (int u = 0; u < 8; ++u) o[u] = f2bf(fmaxf(v[u], 0.f));
        *(int4*)((unsigned short*)yout + (size_t)n * F + c8) = *(int4*)o;
    } else {
        f32x4* yp = (f32x4*)((float*)yout + (size_t)n * F + c8);
        __builtin_nontemporal_store((f32x4){v[0], v[1], v[2], v[3]}, yp);
        __builtin_nontemporal_store((f32x4){v[4], v[5], v[6], v[7]}, yp + 1);
    }
}

// ================= launch =================
extern "C" void kernel_launch(void* const* d_in, const int* in_sizes, int n_in,
                              void* d_out, int out_size, void* d_ws, size_t ws_size,
                              hipStream_t stream)
{
    const int N = 100000, E = 800000, C = 64, H = 128;
    const int Npad = ((N + 63) / 64) * 64;          // 100032

    const float* x       = (const float*)d_in[0];
    const int*   ei      = (const int*)d_in[1];
    const int*   src     = ei;
    const int*   dst     = ei + E;
    const float* W1_in   = (const float*)d_in[2];
    const float* W1_out  = (const float*)d_in[3];
    const float* W1_root = (const float*)d_in[4];
    const float* b1      = (const float*)d_in[5];
    const float* W2_in   = (const float*)d_in[6];
    const float* W2_out  = (const float*)d_in[7];
    const float* W2_root = (const float*)d_in[8];
    const float* b2      = (const float*)d_in[9];
    float* out = (float*)d_out;

    // ---- workspace layout ----
    char* p = (char*)d_ws;
    int*   bcnt_in  = (int*)p;            p += (size_t)(2 * NB + 8) * 4;
    int*   bcnt_out = bcnt_in + NB;
    float* dinv_in  = (float*)p;          p += (size_t)N * 4;
    float* dinv_out = (float*)p;          p += (size_t)N * 4;
    int*   rp_in    = (int*)p;            p += (size_t)(N + 8) * 4;
    int*   rp_out   = (int*)p;            p += (size_t)(N + 8) * 4;
    int*   col_in   = (int*)p;            p += (size_t)E * 4;
    int*   col_out  = (int*)p;            p += (size_t)E * 4;
    int*   ebuf_in  = (int*)p;            p += (size_t)NB * CAP * 4;
    int*   ebuf_out = (int*)p;            p += (size_t)NB * CAP * 4;
    unsigned short* wt1 = (unsigned short*)p;       p += (size_t)384 * 128 * 2;
    unsigned short* wt2 = (unsigned short*)p;       p += (size_t)192 * 128 * 2;
    unsigned short* xb  = (unsigned short*)p;       p += (size_t)Npad * 128 * 2;  // layer-2 input
    unsigned short* y1b = (unsigned short*)p;       p += (size_t)Npad * 128 * 2;  // root outputs
    unsigned short* h_in = (unsigned short*)p;      p += (size_t)Npad * 128 * 2;
    unsigned short* h_out= (unsigned short*)p;      p += (size_t)Npad * 128 * 2;

    const dim3 blk(256);

    // ---- weights + bcnt zero (independent, first) ----
    wtrans_all_k<<<288, blk, 0, stream>>>(W1_root, W1_in, W1_out, W2_root, W2_in, W2_out,
                                          wt1, wt2, bcnt_in);

    // ---- fused: bscatter (blocks 0..255) || layer-1 GEMM (no dinv dependency) ----
    fused1_k<<<SBLK + GEMM_BLOCKS, blk, 0, stream>>>(
        x, wt1, b1, y1b, h_in, h_out,
        src, dst, bcnt_in, bcnt_out, ebuf_in, ebuf_out, N, E);

    // ---- per-bucket build (inline bucket scan): dinv, rp, col ----
    bdegfill_k<<<2 * NB, 512, 0, stream>>>(ebuf_in, ebuf_out, bcnt_in, bcnt_out,
                                           dinv_in, dinv_out,
                                           rp_in, rp_out, col_in, col_out, N, E);

    const int ga1 = (N * (H / 8) + 255) / 256;
    const int ga2 = (N * (C / 8) + 255) / 256;

    // ---- layer 1 gather (per-edge dinv weights): xb = bf16(relu(y1b + msgs)) ----
    gather2_k<128, true, true><<<ga1, blk, 0, stream>>>(
        h_in, h_out, rp_in, col_in, rp_out, col_out,
        dinv_in, dinv_out, y1b, xb, N);

    // ---- layer 2 ----
    gemm2_k<<<GEMM_BLOCKS, blk, 0, stream>>>(
        xb, wt2, b2, dinv_in, dinv_out, y1b, h_in, h_out, N);
    gather2_k<64, false, false><<<ga2, blk, 0, stream>>>(
        h_in, h_out, rp_in, col_in, rp_out, col_out,
        dinv_in, dinv_out, y1b, out, N);
}